// Round 10
// baseline (119.123 us; speedup 1.0000x reference)
//
#include <hip/hip_runtime.h>

#define T_LEN 2048
#define CH 64
#define NH 8
#define STILE 64      // keys per block-iteration (split 2 ways across ws)
#define TTILE 256     // queries per block (split 8 ways across wt)
#define WT 32         // queries per wave
#define NIT (T_LEN / STILE)   // 32
#define CSK 68        // k_hi row stride (bf16), b64 access
#define CS 72         // v_s row stride (bf16), 16B-aligned rows (b128-safe)
#define QS 260        // f32 t-stride for Q staging (16B-aligned rows)
#define RS 68         // f32 c-stride for O reduction

// scale = ch^-0.5 (=1/8) * log2(e), folded into Q; softmax uses exp2 directly.
#define QSCALE 0.180336880972948929f

typedef __attribute__((ext_vector_type(4))) float  f32x4;
typedef __attribute__((ext_vector_type(8))) __bf16 bf16x8;
typedef __attribute__((ext_vector_type(4))) __bf16 bf16x4;
typedef __attribute__((ext_vector_type(2))) __bf16 bf16x2;
typedef __attribute__((ext_vector_type(2))) unsigned int uint2v;
typedef __attribute__((ext_vector_type(4))) unsigned int uint4v;

union SMem {
  float qstage[CH * QS];                  // 66560 B (pre-loop only)
  struct {
    __bf16 k_hi[2][STILE * CSK];          // 2 x 8704 B  (K^T, double-buffered)
    __bf16 v_s [2][CH * CS];              // 2 x 9216 B  (V, double-buffered)
  } loop;                                 // 35840 B
  struct {
    float o[8][WT][RS];                   // 69632 B  O^T partial exchange [wt][t][c]
    float l[2][8][4][16];                 // 4096 B   l partial [nb][wt][quad][tn]
  } red;                                  // union max = 73728 B -> 1 block/CU
};

#define MFMA(A, B, C) __builtin_amdgcn_mfma_f32_16x16x32_bf16((A), (B), (C), 0, 0, 0)

// pack two f32 -> one u32 of 2 bf16 (compiler emits v_cvt_pk_bf16_f32)
__device__ __forceinline__ unsigned pkbf2(float lo, float hi) {
  bf16x2 t = {(__bf16)lo, (__bf16)hi};
  return __builtin_bit_cast(unsigned, t);
}

// ---- staging helpers (512-thread versions; ltid in [0,512)) ----
__device__ __forceinline__ void load_k(const float* kp, int s0, int ltid, float2 (&kreg)[4]) {
  int cq  = ltid >> 5;                    // c-quad 0..15
  int sp2 = ltid & 31;                    // s-pair index
  const float* kc = kp + (size_t)(4 * cq) * T_LEN + s0 + 2 * sp2;
#pragma unroll
  for (int r = 0; r < 4; ++r)
    kreg[r] = *(const float2*)(kc + (size_t)r * T_LEN);
}

__device__ __forceinline__ void store_k(__bf16* kh, int ltid, const float2 (&kreg)[4]) {
  int cq  = ltid >> 5;
  int sp2 = ltid & 31;
  bf16x4 w0 = {(__bf16)kreg[0].x, (__bf16)kreg[1].x, (__bf16)kreg[2].x, (__bf16)kreg[3].x};
  bf16x4 w1 = {(__bf16)kreg[0].y, (__bf16)kreg[1].y, (__bf16)kreg[2].y, (__bf16)kreg[3].y};
  *(bf16x4*)&kh[(2 * sp2 + 0) * CSK + 4 * cq] = w0;
  *(bf16x4*)&kh[(2 * sp2 + 1) * CSK + 4 * cq] = w1;
}

__device__ __forceinline__ void load_v(const float* vp, int s0, int ltid, f32x4 (&vreg)[2]) {
#pragma unroll
  for (int rr = 0; rr < 2; ++rr) {
    int fidx = rr * 512 + ltid;
    int c  = fidx >> 4;
    int s4 = (fidx & 15) << 2;
    vreg[rr] = *(const f32x4*)(vp + (size_t)c * T_LEN + s0 + s4);
  }
}

__device__ __forceinline__ void store_v(__bf16* vs, int ltid, const f32x4 (&vreg)[2]) {
#pragma unroll
  for (int rr = 0; rr < 2; ++rr) {
    int fidx = rr * 512 + ltid;
    int c  = fidx >> 4;
    int s4 = (fidx & 15) << 2;
    bf16x4 vv = {(__bf16)vreg[rr].x, (__bf16)vreg[rr].y,
                 (__bf16)vreg[rr].z, (__bf16)vreg[rr].w};
    *(bf16x4*)&vs[c * CS + s4] = vv;
  }
}

// NOTE (journal): acc lives in AGPRs (unified file; VGPR_Count shows arch
// VGPRs only). R6/R7 spills were the non-acc side. R8: early stores hurt
// (prefetch needs full-iteration slack). R9: cross-iter PV neutral-negative
// (barrier re-aligns waves; inter-wave overlap already covers it).
__global__ __launch_bounds__(1024, 4)
void qkv_attn_mfma(const float* __restrict__ qkv, float* __restrict__ out) {
  __shared__ SMem sm;
  const int tid  = threadIdx.x;
  const int lane = tid & 63;
  const int wave = tid >> 6;     // 0..15
  const int wt   = wave & 7;     // t-eighth (32 queries each)
  const int ws   = wave >> 3;    // s-half; also staging role (0=K, 1=V)
  const int tn   = lane & 15;
  const int quad = lane >> 4;
  const int stid = tid & 511;    // local tid within staging half

  // ---- XCD-aware swizzle: 256 blocks, 8 XCDs -> 32-block chunks per XCD.
  const int d0 = blockIdx.x;
  const int w  = ((d0 & 7) << 5) | (d0 >> 3);
  const int ttile = w & 7;                 // 0..7
  const int bh    = w >> 3;                // 0..31
  const int b = bh >> 3, h = bh & 7;
  const size_t base = (size_t)b * (3 * NH * CH) * T_LEN;
  const float* qp = qkv + base + (size_t)(CH * h) * T_LEN;
  const float* kp = qkv + base + (size_t)(CH * (NH + h)) * T_LEN;
  const float* vp = qkv + base + (size_t)(CH * (2 * NH + h)) * T_LEN;
  const int t0 = ttile * TTILE;

  // ---- stage Q tile fp32 [c][t_local]  (64c x 256t = 16 f32/thread)
#pragma unroll
  for (int rr = 0; rr < 4; ++rr) {
    int fidx = rr * 1024 + tid;
    int c  = fidx >> 6;
    int t4 = (fidx & 63) << 2;
    f32x4 q4 = *(const f32x4*)(qp + (size_t)c * T_LEN + t0 + t4);
    *(f32x4*)&sm.qstage[c * QS + t4] = q4;
  }
  __syncthreads();

  // ---- build Q B-fragments: B[k=c][n=t]
  bf16x8 qh[2][2];                         // [nb][kb]
#pragma unroll
  for (int nb = 0; nb < 2; ++nb)
#pragma unroll
    for (int kb = 0; kb < 2; ++kb) {
      int tloc = wt * WT + nb * 16 + tn;
      bf16x8 H;
#pragma unroll
      for (int j = 0; j < 8; ++j) {
        float qv = sm.qstage[(kb * 32 + quad * 8 + j) * QS + tloc] * QSCALE;
        H[j] = (__bf16)qv;
      }
      qh[nb][kb] = H;
    }
  __syncthreads();   // qstage memory reused by loop arrays below

  f32x4 acc[4][2];                         // O^T partial (this ws): [mbc=c][nb=t]
  f32x4 acc_l[2];                          // l partial via ones-MFMA: [nb]
#pragma unroll
  for (int mbc = 0; mbc < 4; ++mbc)
#pragma unroll
    for (int nb = 0; nb < 2; ++nb)
      acc[mbc][nb] = (f32x4){0.f, 0.f, 0.f, 0.f};
  acc_l[0] = (f32x4){0.f, 0.f, 0.f, 0.f};
  acc_l[1] = (f32x4){0.f, 0.f, 0.f, 0.f};

  // ones A-fragment: l[t] = sum_s 1 * P[s][t] (every output row = full l)
  bf16x8 av_one;
#pragma unroll
  for (int j = 0; j < 8; ++j) av_one[j] = (__bf16)1.0f;

  // ---- prologue: stage tile 0 (waves 0-7 stage K, waves 8-15 stage V)
  float2 kreg[4];
  f32x4  vreg[2];
  if (ws == 0) { load_k(kp, 0, stid, kreg); store_k(sm.loop.k_hi[0], stid, kreg); }
  else         { load_v(vp, 0, stid, vreg); store_v(sm.loop.v_s[0], stid, vreg); }
  __syncthreads();

  for (int it = 0; it < NIT; ++it) {
    const int cur = it & 1;
    const bool more = (it + 1 < NIT);

    // ---- global prefetch of tile it+1 (latency hidden under QK/softmax/PV)
    if (more) {
      if (ws == 0) load_k(kp, (it + 1) * STILE, stid, kreg);
      else         load_v(vp, (it + 1) * STILE, stid, vreg);
    }

    // ---- QK(it): wave's s-half (2 mb rows), its t-eighth
    const __bf16* kh = sm.loop.k_hi[cur];
    bf16x8 ah[2][2];
#pragma unroll
    for (int mb = 0; mb < 2; ++mb) {
      const int srow = (32 * ws + 16 * mb + tn) * CSK;
#pragma unroll
      for (int kb = 0; kb < 2; ++kb) {
        bf16x4 a0 = *(const bf16x4*)&kh[srow + 32 * kb + quad * 8];
        bf16x4 a1 = *(const bf16x4*)&kh[srow + 32 * kb + quad * 8 + 4];
        ah[mb][kb] = __builtin_shufflevector(a0, a1, 0, 1, 2, 3, 4, 5, 6, 7);
      }
    }
    f32x4 d[2][2];
#pragma unroll
    for (int mb = 0; mb < 2; ++mb)
#pragma unroll
      for (int nb = 0; nb < 2; ++nb) {
        f32x4 t = (f32x4){0.f, 0.f, 0.f, 0.f};
        t = MFMA(ah[mb][0], qh[nb][0], t);
        t = MFMA(ah[mb][1], qh[nb][1], t);
        d[mb][nb] = t;
      }

    // ---- issue V fragment reads early (latency hidden under softmax VALU)
    const __bf16* vs = sm.loop.v_s[cur];
    bf16x8 av[4];
#pragma unroll
    for (int mbc = 0; mbc < 4; ++mbc)
      av[mbc] = *(const bf16x8*)&vs[(16 * mbc + tn) * CS + 32 * ws + quad * 8];

    // ---- p = exp2(s'), then in-register redistribution to PV B-fragment.
    // QK C/D layout: lane(q,tn) holds P[s=16mb+4q+r][t=tn]. PV B-frag needs
    // P[s=8q+j][t=tn]. (w0,w2)=SW16(SW32(u00,u10)); (w1,w3)=SW16(SW32(u01,u11)).
    // NO rs adds: l comes from the ones-MFMA below.
    bf16x8 bp[2];
#pragma unroll
    for (int nb = 0; nb < 2; ++nb) {
#pragma unroll
      for (int mb = 0; mb < 2; ++mb)
#pragma unroll
        for (int r = 0; r < 4; ++r)
          d[mb][nb][r] = __builtin_amdgcn_exp2f(d[mb][nb][r]);
      unsigned u00 = pkbf2(d[0][nb][0], d[0][nb][1]);
      unsigned u01 = pkbf2(d[0][nb][2], d[0][nb][3]);
      unsigned u10 = pkbf2(d[1][nb][0], d[1][nb][1]);
      unsigned u11 = pkbf2(d[1][nb][2], d[1][nb][3]);
      uint2v s0 = __builtin_amdgcn_permlane32_swap(u00, u10, false, false);
      uint2v r0 = __builtin_amdgcn_permlane16_swap(s0.x, s0.y, false, false);
      uint2v s1 = __builtin_amdgcn_permlane32_swap(u01, u11, false, false);
      uint2v r1 = __builtin_amdgcn_permlane16_swap(s1.x, s1.y, false, false);
      uint4v wv = {r0.x, r1.x, r0.y, r1.y};   // w0,w1,w2,w3 -> j=0..7
      bp[nb] = __builtin_bit_cast(bf16x8, wv);
    }

    // ---- PV(it) + l via ones-row MFMA (full 32-key column sums)
#pragma unroll
    for (int mbc = 0; mbc < 4; ++mbc)
#pragma unroll
      for (int nb = 0; nb < 2; ++nb)
        acc[mbc][nb] = MFMA(av[mbc], bp[nb], acc[mbc][nb]);
#pragma unroll
    for (int nb = 0; nb < 2; ++nb)
      acc_l[nb] = MFMA(av_one, bp[nb], acc_l[nb]);

    // ---- stage tile it+1 LATE (prefetch had the whole iteration in flight)
    if (more) {
      if (ws == 0) store_k(sm.loop.k_hi[cur ^ 1], stid, kreg);
      else         store_v(sm.loop.v_s [cur ^ 1], stid, vreg);
    }
    __syncthreads();
  }

  // l_part[nb]: every row of the ones-MFMA tile equals the full column sum
  // over this ws's keys, so any one register slot is the complete partial.
  float l_part[2] = {acc_l[0][0], acc_l[1][0]};

  // ---- cross-ws reduction: ws=1 publishes partials, ws=0 combines + stores
  if (ws == 1) {
#pragma unroll
    for (int nb = 0; nb < 2; ++nb) {
      sm.red.l[nb][wt][quad][tn] = l_part[nb];
#pragma unroll
      for (int mbc = 0; mbc < 4; ++mbc)
        *(f32x4*)&sm.red.o[wt][nb * 16 + tn][16 * mbc + quad * 4] = acc[mbc][nb];
    }
  }
  __syncthreads();
  if (ws == 0) {
    float* op = out + (size_t)bh * CH * T_LEN;
#pragma unroll
    for (int nb = 0; nb < 2; ++nb) {
      // full-tile sums already include all 4 quads -> NO shfl reduction here
      float l = l_part[nb] + sm.red.l[nb][wt][quad][tn];
      float inv_l = 1.0f / l;
      int t = t0 + wt * WT + nb * 16 + tn;
#pragma unroll
      for (int mbc = 0; mbc < 4; ++mbc) {
        f32x4 o = acc[mbc][nb] + *(const f32x4*)&sm.red.o[wt][nb * 16 + tn][16 * mbc + quad * 4];
        o = o * inv_l;
        int c = 16 * mbc + quad * 4;
        op[(size_t)(c + 0) * T_LEN + t] = o.x;
        op[(size_t)(c + 1) * T_LEN + t] = o.y;
        op[(size_t)(c + 2) * T_LEN + t] = o.z;
        op[(size_t)(c + 3) * T_LEN + t] = o.w;
      }
    }
  }
}

extern "C" void kernel_launch(void* const* d_in, const int* in_sizes, int n_in,
                              void* d_out, int out_size, void* d_ws, size_t ws_size,
                              hipStream_t stream) {
  const float* qkv = (const float*)d_in[0];
  float* out = (float*)d_out;
  dim3 grid(256);   // 256 blocks of 1024 threads (XCD-swizzled in-kernel)
  qkv_attn_mfma<<<grid, 1024, 0, stream>>>(qkv, out);
}

// Round 11
// 117.148 us; speedup vs baseline: 1.0169x; 1.0169x over previous
//
#include <hip/hip_runtime.h>

#define T_LEN 2048
#define CH 64
#define NH 8
#define STILE 64      // keys per block-iteration (split 2 ways across ws)
#define TTILE 256     // queries per block (split 8 ways across wt)
#define WT 32         // queries per wave
#define NIT (T_LEN / STILE)   // 32
#define KSZ (STILE * CH)      // k_hi elems per buffer (64 rows x 64 cols, no pad)
#define CS 72         // v_s row stride (bf16), 16B-aligned rows (b128-safe)
#define QS 260        // f32 t-stride for Q staging (16B-aligned rows)
#define RS 68         // f32 c-stride for O reduction

// scale = ch^-0.5 (=1/8) * log2(e), folded into Q; softmax uses exp2 directly.
#define QSCALE 0.180336880972948929f

typedef __attribute__((ext_vector_type(4))) float  f32x4;
typedef __attribute__((ext_vector_type(8))) __bf16 bf16x8;
typedef __attribute__((ext_vector_type(4))) __bf16 bf16x4;
typedef __attribute__((ext_vector_type(2))) __bf16 bf16x2;
typedef __attribute__((ext_vector_type(2))) unsigned int uint2v;
typedef __attribute__((ext_vector_type(4))) unsigned int uint4v;

union SMem {
  float qstage[CH * QS];                  // 66560 B (pre-loop only)
  struct {
    __bf16 k_hi[2][KSZ];                  // 2 x 8192 B  (K^T, XOR-swizzled rows)
    __bf16 v_s [2][CH * CS];              // 2 x 9216 B  (V, double-buffered)
  } loop;                                 // 34816 B
  struct {
    float o[8][WT][RS];                   // 69632 B  O^T partial exchange [wt][t][c]
    float l[2][8][4][16];                 // 4096 B   l partial [nb][wt][quad][tn]
  } red;                                  // union max = 73728 B -> 1 block/CU
};

#define MFMA(A, B, C) __builtin_amdgcn_mfma_f32_16x16x32_bf16((A), (B), (C), 0, 0, 0)

// pack two f32 -> one u32 of 2 bf16 (compiler emits v_cvt_pk_bf16_f32)
__device__ __forceinline__ unsigned pkbf2(float lo, float hi) {
  bf16x2 t = {(__bf16)lo, (__bf16)hi};
  return __builtin_bit_cast(unsigned, t);
}

// ---- K staging: row s (key), cols 8cg..8cg+7 (channels), XOR-swizzled.
// Swizzle: elem ^= ((s&7)<<3) — bits 3..5 of the element offset (col-group).
// Store slot = cg^(s&7); read of group g fetches slot g^(s&7) -> involution.
// Bank math (verified): store start-slot = cg^(lane&7)  -> 8 lanes/slot, 8
// rounds for 1024B = conflict-free.  Read start-slot = (4kb+quad)^(tn&7) ->
// 8 lanes/slot = conflict-free b128.
__device__ __forceinline__ void load_k8(const float* kp, int s0, int stid, float (&kr)[8]) {
  int s  = stid & 63;                     // key column
  int cg = stid >> 6;                     // channel group 0..7
  const float* kc = kp + (size_t)(8 * cg) * T_LEN + s0 + s;
#pragma unroll
  for (int j = 0; j < 8; ++j)
    kr[j] = kc[(size_t)j * T_LEN];        // 64 lanes read 64 consecutive s: coalesced
}

__device__ __forceinline__ void store_k8(__bf16* kh, int stid, const float (&kr)[8]) {
  int s  = stid & 63;
  int cg = stid >> 6;
  bf16x8 w;
#pragma unroll
  for (int j = 0; j < 8; ++j) w[j] = (__bf16)kr[j];
  int e = (s << 6) + (cg << 3);
  *(bf16x8*)&kh[e ^ ((s & 7) << 3)] = w;
}

__device__ __forceinline__ void load_v(const float* vp, int s0, int ltid, f32x4 (&vreg)[2]) {
#pragma unroll
  for (int rr = 0; rr < 2; ++rr) {
    int fidx = rr * 512 + ltid;
    int c  = fidx >> 4;
    int s4 = (fidx & 15) << 2;
    vreg[rr] = *(const f32x4*)(vp + (size_t)c * T_LEN + s0 + s4);
  }
}

__device__ __forceinline__ void store_v(__bf16* vs, int ltid, const f32x4 (&vreg)[2]) {
#pragma unroll
  for (int rr = 0; rr < 2; ++rr) {
    int fidx = rr * 512 + ltid;
    int c  = fidx >> 4;
    int s4 = (fidx & 15) << 2;
    bf16x4 vv = {(__bf16)vreg[rr].x, (__bf16)vreg[rr].y,
                 (__bf16)vreg[rr].z, (__bf16)vreg[rr].w};
    *(bf16x4*)&vs[c * CS + s4] = vv;
  }
}

// NOTE (journal): acc lives in AGPRs (unified file; VGPR_Count shows arch
// VGPRs only). R6/R7 spills were the non-acc side. R8: early stores hurt
// (prefetch needs full-iteration slack). R9: cross-iter PV neutral-negative.
// R10: ones-MFMA l-sum is a win (-2us). R11: conflict-free swizzled K tile.
__global__ __launch_bounds__(1024, 4)
void qkv_attn_mfma(const float* __restrict__ qkv, float* __restrict__ out) {
  __shared__ SMem sm;
  const int tid  = threadIdx.x;
  const int lane = tid & 63;
  const int wave = tid >> 6;     // 0..15
  const int wt   = wave & 7;     // t-eighth (32 queries each)
  const int ws   = wave >> 3;    // s-half; also staging role (0=K, 1=V)
  const int tn   = lane & 15;
  const int quad = lane >> 4;
  const int stid = tid & 511;    // local tid within staging half

  // ---- XCD-aware swizzle: 256 blocks, 8 XCDs -> 32-block chunks per XCD.
  const int d0 = blockIdx.x;
  const int w  = ((d0 & 7) << 5) | (d0 >> 3);
  const int ttile = w & 7;                 // 0..7
  const int bh    = w >> 3;                // 0..31
  const int b = bh >> 3, h = bh & 7;
  const size_t base = (size_t)b * (3 * NH * CH) * T_LEN;
  const float* qp = qkv + base + (size_t)(CH * h) * T_LEN;
  const float* kp = qkv + base + (size_t)(CH * (NH + h)) * T_LEN;
  const float* vp = qkv + base + (size_t)(CH * (2 * NH + h)) * T_LEN;
  const int t0 = ttile * TTILE;

  // ---- stage Q tile fp32 [c][t_local]  (64c x 256t = 16 f32/thread)
#pragma unroll
  for (int rr = 0; rr < 4; ++rr) {
    int fidx = rr * 1024 + tid;
    int c  = fidx >> 6;
    int t4 = (fidx & 63) << 2;
    f32x4 q4 = *(const f32x4*)(qp + (size_t)c * T_LEN + t0 + t4);
    *(f32x4*)&sm.qstage[c * QS + t4] = q4;
  }
  __syncthreads();

  // ---- build Q B-fragments: B[k=c][n=t]
  bf16x8 qh[2][2];                         // [nb][kb]
#pragma unroll
  for (int nb = 0; nb < 2; ++nb)
#pragma unroll
    for (int kb = 0; kb < 2; ++kb) {
      int tloc = wt * WT + nb * 16 + tn;
      bf16x8 H;
#pragma unroll
      for (int j = 0; j < 8; ++j) {
        float qv = sm.qstage[(kb * 32 + quad * 8 + j) * QS + tloc] * QSCALE;
        H[j] = (__bf16)qv;
      }
      qh[nb][kb] = H;
    }
  __syncthreads();   // qstage memory reused by loop arrays below

  f32x4 acc[4][2];                         // O^T partial (this ws): [mbc=c][nb=t]
  f32x4 acc_l[2];                          // l partial via ones-MFMA: [nb]
#pragma unroll
  for (int mbc = 0; mbc < 4; ++mbc)
#pragma unroll
    for (int nb = 0; nb < 2; ++nb)
      acc[mbc][nb] = (f32x4){0.f, 0.f, 0.f, 0.f};
  acc_l[0] = (f32x4){0.f, 0.f, 0.f, 0.f};
  acc_l[1] = (f32x4){0.f, 0.f, 0.f, 0.f};

  // ones A-fragment: l[t] = sum_s 1 * P[s][t] (every output row = full l)
  bf16x8 av_one;
#pragma unroll
  for (int j = 0; j < 8; ++j) av_one[j] = (__bf16)1.0f;

  // ---- prologue: stage tile 0 (waves 0-7 stage K, waves 8-15 stage V)
  float  kreg[8];
  f32x4  vreg[2];
  if (ws == 0) { load_k8(kp, 0, stid, kreg); store_k8(sm.loop.k_hi[0], stid, kreg); }
  else         { load_v (vp, 0, stid, vreg); store_v (sm.loop.v_s[0], stid, vreg); }
  __syncthreads();

  for (int it = 0; it < NIT; ++it) {
    const int cur = it & 1;
    const bool more = (it + 1 < NIT);

    // ---- global prefetch of tile it+1 (latency hidden under QK/softmax/PV)
    if (more) {
      if (ws == 0) load_k8(kp, (it + 1) * STILE, stid, kreg);
      else         load_v (vp, (it + 1) * STILE, stid, vreg);
    }

    // ---- QK(it): wave's s-half (2 mb rows), its t-eighth.
    // Single b128 per (mb,kb), conflict-free via the K swizzle.
    const __bf16* kh = sm.loop.k_hi[cur];
    const int swz = (tn & 7) << 3;
    bf16x8 ah[2][2];
#pragma unroll
    for (int mb = 0; mb < 2; ++mb) {
      const int srow = 32 * ws + 16 * mb + tn;          // srow&7 == tn&7
#pragma unroll
      for (int kb = 0; kb < 2; ++kb) {
        int e = (srow << 6) + 32 * kb + 8 * quad;
        ah[mb][kb] = *(const bf16x8*)&kh[e ^ swz];
      }
    }
    f32x4 d[2][2];
#pragma unroll
    for (int mb = 0; mb < 2; ++mb)
#pragma unroll
      for (int nb = 0; nb < 2; ++nb) {
        f32x4 t = (f32x4){0.f, 0.f, 0.f, 0.f};
        t = MFMA(ah[mb][0], qh[nb][0], t);
        t = MFMA(ah[mb][1], qh[nb][1], t);
        d[mb][nb] = t;
      }

    // ---- issue V fragment reads early (latency hidden under softmax VALU)
    const __bf16* vs = sm.loop.v_s[cur];
    bf16x8 av[4];
#pragma unroll
    for (int mbc = 0; mbc < 4; ++mbc)
      av[mbc] = *(const bf16x8*)&vs[(16 * mbc + tn) * CS + 32 * ws + quad * 8];

    // ---- p = exp2(s'), then in-register redistribution to PV B-fragment.
    // QK C/D layout: lane(q,tn) holds P[s=16mb+4q+r][t=tn]. PV B-frag needs
    // P[s=8q+j][t=tn]. (w0,w2)=SW16(SW32(u00,u10)); (w1,w3)=SW16(SW32(u01,u11)).
    bf16x8 bp[2];
#pragma unroll
    for (int nb = 0; nb < 2; ++nb) {
#pragma unroll
      for (int mb = 0; mb < 2; ++mb)
#pragma unroll
        for (int r = 0; r < 4; ++r)
          d[mb][nb][r] = __builtin_amdgcn_exp2f(d[mb][nb][r]);
      unsigned u00 = pkbf2(d[0][nb][0], d[0][nb][1]);
      unsigned u01 = pkbf2(d[0][nb][2], d[0][nb][3]);
      unsigned u10 = pkbf2(d[1][nb][0], d[1][nb][1]);
      unsigned u11 = pkbf2(d[1][nb][2], d[1][nb][3]);
      uint2v s0 = __builtin_amdgcn_permlane32_swap(u00, u10, false, false);
      uint2v r0 = __builtin_amdgcn_permlane16_swap(s0.x, s0.y, false, false);
      uint2v s1 = __builtin_amdgcn_permlane32_swap(u01, u11, false, false);
      uint2v r1 = __builtin_amdgcn_permlane16_swap(s1.x, s1.y, false, false);
      uint4v wv = {r0.x, r1.x, r0.y, r1.y};   // w0,w1,w2,w3 -> j=0..7
      bp[nb] = __builtin_bit_cast(bf16x8, wv);
    }

    // ---- PV(it) + l via ones-row MFMA (full 32-key column sums)
#pragma unroll
    for (int mbc = 0; mbc < 4; ++mbc)
#pragma unroll
      for (int nb = 0; nb < 2; ++nb)
        acc[mbc][nb] = MFMA(av[mbc], bp[nb], acc[mbc][nb]);
#pragma unroll
    for (int nb = 0; nb < 2; ++nb)
      acc_l[nb] = MFMA(av_one, bp[nb], acc_l[nb]);

    // ---- stage tile it+1 LATE (prefetch had the whole iteration in flight)
    if (more) {
      if (ws == 0) store_k8(sm.loop.k_hi[cur ^ 1], stid, kreg);
      else         store_v (sm.loop.v_s [cur ^ 1], stid, vreg);
    }
    __syncthreads();
  }

  // l_part[nb]: every row of the ones-MFMA tile equals the full column sum
  // over this ws's keys, so any one register slot is the complete partial.
  float l_part[2] = {acc_l[0][0], acc_l[1][0]};

  // ---- cross-ws reduction: ws=1 publishes partials, ws=0 combines + stores
  if (ws == 1) {
#pragma unroll
    for (int nb = 0; nb < 2; ++nb) {
      sm.red.l[nb][wt][quad][tn] = l_part[nb];
#pragma unroll
      for (int mbc = 0; mbc < 4; ++mbc)
        *(f32x4*)&sm.red.o[wt][nb * 16 + tn][16 * mbc + quad * 4] = acc[mbc][nb];
    }
  }
  __syncthreads();
  if (ws == 0) {
    float* op = out + (size_t)bh * CH * T_LEN;
#pragma unroll
    for (int nb = 0; nb < 2; ++nb) {
      // full-tile sums already include all 4 quads -> NO shfl reduction here
      float l = l_part[nb] + sm.red.l[nb][wt][quad][tn];
      float inv_l = 1.0f / l;
      int t = t0 + wt * WT + nb * 16 + tn;
#pragma unroll
      for (int mbc = 0; mbc < 4; ++mbc) {
        f32x4 o = acc[mbc][nb] + *(const f32x4*)&sm.red.o[wt][nb * 16 + tn][16 * mbc + quad * 4];
        o = o * inv_l;
        int c = 16 * mbc + quad * 4;
        op[(size_t)(c + 0) * T_LEN + t] = o.x;
        op[(size_t)(c + 1) * T_LEN + t] = o.y;
        op[(size_t)(c + 2) * T_LEN + t] = o.z;
        op[(size_t)(c + 3) * T_LEN + t] = o.w;
      }
    }
  }
}

extern "C" void kernel_launch(void* const* d_in, const int* in_sizes, int n_in,
                              void* d_out, int out_size, void* d_ws, size_t ws_size,
                              hipStream_t stream) {
  const float* qkv = (const float*)d_in[0];
  float* out = (float*)d_out;
  dim3 grid(256);   // 256 blocks of 1024 threads (XCD-swizzled in-kernel)
  qkv_attn_mfma<<<grid, 1024, 0, stream>>>(qkv, out);
}